// Round 22
// baseline (48.297 us; speedup 1.0000x reference)
//
#include <hip/hip_runtime.h>

typedef _Float16 f16x8 __attribute__((ext_vector_type(8)));
typedef _Float16 f16x4 __attribute__((ext_vector_type(4)));
typedef float    f32x4 __attribute__((ext_vector_type(4)));
typedef unsigned int u32x4 __attribute__((ext_vector_type(4)));

constexpr int NTOK   = 1568;       // T*H*W = 8*14*14
constexpr int NHEADS = 8;
constexpr int NCH    = 512;
constexpr int NC32   = 52;         // 32-token chunks, padded to 1664 tokens
constexpr float SK   = 0.15014030f; // 0.125*sqrt(log2 e): (q*SK)·(k*SK) = s*log2e/64 -> p = exp2(.)
constexpr size_t IMG_BH = (size_t)NC32 * 4096;   // 212992 B per (bh) per image

// ---- pre-pass: build fragment-major K and V images (every frag = contiguous 1KB, lane*16) ----
// K frag (c16 = tok/16, ks): slot(l15,grp,j) = x[tok=c16*16+l15][d=ks*32+8grp+j] * SK
// V frag (c32 = tok/32, db): slot(l15,grp,j) = x[tok=c32*32+16*(j>>2)+4grp+(j&3)][d=db*16+l15]
__global__ __launch_bounds__(256)
void prep_kernel(const float* __restrict__ x, char* __restrict__ Kimg, char* __restrict__ Vimg)
{
    const int bh = blockIdx.x, c32 = blockIdx.y;
    const int b = bh >> 3, h = bh & 7;
    const int t = threadIdx.x;
    const int f = t >> 6, l = t & 63, l15 = l & 15, grp = l >> 4;

    char* Kg = Kimg + (size_t)bh * IMG_BH + (size_t)(c32 * 4 + f) * 1024 + l * 16;
    char* Vg = Vimg + (size_t)bh * IMG_BH + (size_t)(c32 * 4 + f) * 1024 + l * 16;

    const int n0 = c32 * 32;
    if (n0 >= NTOK) {                       // pure padding chunk: zeros (K=0 -> p=1, V=0)
        f16x8 z;
#pragma unroll
        for (int j = 0; j < 8; ++j) z[j] = (_Float16)0.f;
        *(f16x8*)Kg = z; *(f16x8*)Vg = z;
        return;
    }

    __shared__ _Float16 kbuf[32][72];       // [tok][d], scaled
    __shared__ _Float16 vbuf[64][40];       // [d][tok]

    const int tok = t & 31, dhi = t >> 5;   // coalesced: 8 x 128B segments per pass
#pragma unroll
    for (int p = 0; p < 8; ++p) {
        const int d = 8 * p + dhi;
        const float v = x[((size_t)b * NCH + d * NHEADS + h) * NTOK + n0 + tok];
        kbuf[tok][d] = (_Float16)(v * SK);
        vbuf[d][tok] = (_Float16)v;
    }
    __syncthreads();

    // K frag f: cb = f>>1 (16-tok half), ks = f&1
    *(f16x8*)Kg = *(const f16x8*)&kbuf[(f >> 1) * 16 + l15][(f & 1) * 32 + grp * 8];
    // V frag db = f: token quads {4grp..+3} and {16+4grp..+3}
    f16x4 va = *(const f16x4*)&vbuf[f * 16 + l15][4 * grp];
    f16x4 vb = *(const f16x4*)&vbuf[f * 16 + l15][16 + 4 * grp];
    f16x8 vv;
#pragma unroll
    for (int j = 0; j < 4; ++j) { vv[j] = va[j]; vv[4 + j] = vb[j]; }
    *(f16x8*)Vg = vv;
}

// pack 8 exp2(s) values into one P fragment — pure register ops, no union/memory
static __device__ __forceinline__ f16x8 make_bp(f32x4 sA, f32x4 sB)
{
    u32x4 w;
    w[0] = __builtin_bit_cast(unsigned int,
        __builtin_amdgcn_cvt_pkrtz(__builtin_amdgcn_exp2f(sA[0]), __builtin_amdgcn_exp2f(sA[1])));
    w[1] = __builtin_bit_cast(unsigned int,
        __builtin_amdgcn_cvt_pkrtz(__builtin_amdgcn_exp2f(sA[2]), __builtin_amdgcn_exp2f(sA[3])));
    w[2] = __builtin_bit_cast(unsigned int,
        __builtin_amdgcn_cvt_pkrtz(__builtin_amdgcn_exp2f(sB[0]), __builtin_amdgcn_exp2f(sB[1])));
    w[3] = __builtin_bit_cast(unsigned int,
        __builtin_amdgcn_cvt_pkrtz(__builtin_amdgcn_exp2f(sB[2]), __builtin_amdgcn_exp2f(sB[3])));
    return __builtin_bit_cast(f16x8, w);
}

// per-round compute for ONE 16-q-row subtile on ONE 32-token half: QK -> exp -> lsum+PV
static __device__ __forceinline__ void chunk_compute(
    const char* kb, const char* vb, int lane,
    const f16x8 (&aq)[2], const f16x8& ones,
    f32x4 (&oacc)[4], f32x4& lacc)
{
    const f32x4 z4 = {0.f, 0.f, 0.f, 0.f};
    f16x8 k0 = *(const f16x8*)(kb + lane * 16);
    f16x8 k1 = *(const f16x8*)(kb + 1024 + lane * 16);
    f16x8 k2 = *(const f16x8*)(kb + 2048 + lane * 16);
    f16x8 k3 = *(const f16x8*)(kb + 3072 + lane * 16);
    f32x4 sA = __builtin_amdgcn_mfma_f32_16x16x32_f16(k0, aq[0], z4, 0, 0, 0);
    sA = __builtin_amdgcn_mfma_f32_16x16x32_f16(k1, aq[1], sA, 0, 0, 0);
    f32x4 sB = __builtin_amdgcn_mfma_f32_16x16x32_f16(k2, aq[0], z4, 0, 0, 0);
    sB = __builtin_amdgcn_mfma_f32_16x16x32_f16(k3, aq[1], sB, 0, 0, 0);
    const f16x8 bp = make_bp(sA, sB);   // slot j = token 16*(j>>2)+4grp+(j&3)
    f16x8 v0 = *(const f16x8*)(vb + lane * 16);
    f16x8 v1 = *(const f16x8*)(vb + 1024 + lane * 16);
    f16x8 v2 = *(const f16x8*)(vb + 2048 + lane * 16);
    f16x8 v3 = *(const f16x8*)(vb + 3072 + lane * 16);
    lacc    = __builtin_amdgcn_mfma_f32_16x16x32_f16(ones, bp, lacc, 0, 0, 0);
    oacc[0] = __builtin_amdgcn_mfma_f32_16x16x32_f16(v0, bp, oacc[0], 0, 0, 0);
    oacc[1] = __builtin_amdgcn_mfma_f32_16x16x32_f16(v1, bp, oacc[1], 0, 0, 0);
    oacc[2] = __builtin_amdgcn_mfma_f32_16x16x32_f16(v2, bp, oacc[2], 0, 0, 0);
    oacc[3] = __builtin_amdgcn_mfma_f32_16x16x32_f16(v3, bp, oacc[3], 0, 0, 0);
}

// ---- main attention: 8 waves (4 q-subtiles x 2 k-halves), 25 LDS rounds of 64 tokens.
// Low L2 traffic (block-shared staging) + ~6 waves/SIMD + few barrier rounds: the one
// corner of {traffic, residency, sync} space untested by rounds 9-21. ----
__global__ __launch_bounds__(512, 4)
void attn_fwd(const char* __restrict__ Kimg, const char* __restrict__ Vimg,
              float* __restrict__ out)
{
    // XCD-aware bijective remap (800 = 8*100): 4 bh per XCD -> both images L2-resident
    const int orig = blockIdx.x;
    const int wgid = (orig & 7) * 100 + (orig >> 3);
    const int qt = wgid % 25, bh = wgid / 25;       // qt: 64-row q-tile
    const int b = bh >> 3, head = bh & 7;
    const int t = threadIdx.x, wave = t >> 6, lane = t & 63;
    const int qs = wave >> 1, kh = wave & 1;        // q-subtile (16 rows) x k-half (32 tok)
    const int l15 = lane & 15, grp = lane >> 4;

    __shared__ __align__(16) char smem[36864];      // [0,32768): 2x16KB ring; tail: combine
    char* ring0 = smem;                             // K 8KB | V 8KB
    char* ring1 = smem + 16384;

    const char* Kb = Kimg + (size_t)bh * IMG_BH;
    const char* Vb = Vimg + (size_t)bh * IMG_BH;

    // Q fragment for this wave's 16-row subtile (shared by both k-halves of same qs)
    const int s16 = qt * 4 + qs;                    // <= 99 < 104 image subtiles
    f16x8 aq[2];
    aq[0] = *(const f16x8*)(Kb + (size_t)(s16 * 2 + 0) * 1024 + lane * 16);
    aq[1] = *(const f16x8*)(Kb + (size_t)(s16 * 2 + 1) * 1024 + lane * 16);

    f16x8 ones;
#pragma unroll
    for (int j = 0; j < 8; ++j) ones[j] = (_Float16)1.f;

    f32x4 oacc[4];
    f32x4 lacc = {0.f, 0.f, 0.f, 0.f};
#pragma unroll
    for (int db = 0; db < 4; ++db) oacc[db] = f32x4{0.f, 0.f, 0.f, 0.f};

    const int soff = t * 16;        // 512 threads x 16B = 8KB per staged array

    // prologue: stage round 0 (image chunks 0,1 are contiguous 8KB in each image)
    {
        f16x8 sk = *(const f16x8*)(Kb + soff);
        f16x8 sv = *(const f16x8*)(Vb + soff);
        *(f16x8*)(ring0 + soff) = sk;               // K at [0, 8192)
        *(f16x8*)(ring0 + 8192 + soff) = sv;        // V at [8192, 16384)
    }
    __syncthreads();

    for (int c = 0; c < 25; ++c) {  // 25 x 64 tok = 1600 (tokens 1568-1599 are padding)
        char* cur = (c & 1) ? ring1 : ring0;
        char* nxt = (c & 1) ? ring0 : ring1;

        // issue next round's loads early (chunks 2(c+1), 2(c+1)+1 <= 51: inside padded image)
        f16x8 sk = *(const f16x8*)(Kb + (size_t)(c + 1) * 8192 + soff);
        f16x8 sv = *(const f16x8*)(Vb + (size_t)(c + 1) * 8192 + soff);

        // compute my 32-token half from LDS (all access: 64 lanes x consecutive 16B)
        chunk_compute(cur + kh * 4096, cur + 8192 + kh * 4096, lane, aq, ones, oacc, lacc);

        // write staged regs into the other buffer (its reads completed before previous sync)
        *(f16x8*)(nxt + soff) = sk;
        *(f16x8*)(nxt + 8192 + soff) = sv;
        __syncthreads();
    }

    // ---- combine the 2 k-halves per q-subtile (kh=1 -> LDS, kh=0 adds) ----
    float* comb = (float*)smem;     // 4 x 64 x 17 floats = 17.4 KB (barrier-separated reuse)
    if (kh == 1) {
        float* p = comb + (size_t)(qs * 64 + lane) * 17;
#pragma unroll
        for (int db = 0; db < 4; ++db)
#pragma unroll
            for (int q = 0; q < 4; ++q) p[db * 4 + q] = oacc[db][q];
        p[16] = lacc[0];
    }
    __syncthreads();

    if (kh == 0 && s16 < 98) {      // 98*16 = 1568: wave-uniform validity
        const float* p = comb + (size_t)(qs * 64 + lane) * 17;
#pragma unroll
        for (int db = 0; db < 4; ++db)
#pragma unroll
            for (int q = 0; q < 4; ++q) oacc[db][q] += p[db * 4 + q];
        // kh=1's round 24 (tokens 1568-1599) is pure padding: K=0 -> p=1.0 x32 -> subtract
        const float lsum = lacc[0] + p[16] - 32.0f;
        const int qrow = s16 * 16 + l15;
        const float inv = 1.0f / lsum;
#pragma unroll
        for (int db = 0; db < 4; ++db)
#pragma unroll
            for (int q = 0; q < 4; ++q) {
                const int d = db * 16 + 4 * grp + q;     // O^T: row=d, col=q
                out[((size_t)b * NCH + (size_t)d * NHEADS + head) * NTOK + qrow] = oacc[db][q] * inv;
            }
    }
}

extern "C" void kernel_launch(void* const* d_in, const int* in_sizes, int n_in,
                              void* d_out, int out_size, void* d_ws, size_t ws_size,
                              hipStream_t stream)
{
    const float* x = (const float*)d_in[0];
    float* out     = (float*)d_out;

    char* Kimg = (char*)d_ws;                       // 32 * 208KB = 6.8 MB
    char* Vimg = (char*)d_ws + 32 * IMG_BH;         // + 6.8 MB

    dim3 pgrid(32, NC32);                           // 32 bh x 52 chunks
    prep_kernel<<<pgrid, 256, 0, stream>>>(x, Kimg, Vimg);

    attn_fwd<<<800, 512, 0, stream>>>(Kimg, Vimg, out);   // 25 q-tiles x 32 bh, XCD-remapped
}